// Round 5
// baseline (6526.875 us; speedup 1.0000x reference)
//
#include <hip/hip_runtime.h>

typedef __bf16 bf16x8 __attribute__((ext_vector_type(8)));
typedef float f32x4 __attribute__((ext_vector_type(4)));
typedef int i32x4 __attribute__((ext_vector_type(4)));

#define T_STEPS 1024
#define H_SZ    1024
#define F_IN    256
#define NB      16   // batches per group

__device__ __forceinline__ unsigned short f2bf(float f) {
    union { float f; unsigned u; } v; v.f = f;
    unsigned r = v.u + 0x7fffu + ((v.u >> 16) & 1u);
    return (unsigned short)(r >> 16);
}

__device__ __forceinline__ float fsigmoid(float x) {
    return 1.0f / (1.0f + __expf(-x));
}
__device__ __forceinline__ float ftanh(float x) {
    return 1.0f - 2.0f / (__expf(2.0f * x) + 1.0f);
}

// ---------------------------------------------------------------------------
// Gaussian blur (sigma=1, radius=4, edge padding), both axes fused.
// ---------------------------------------------------------------------------
__global__ __launch_bounds__(256) void blur_kernel(
    const float* __restrict__ x, unsigned short* __restrict__ xb)
{
    __shared__ float tb[64][256];
    const float kk[9] = {
        0.000133831f, 0.0044318617f, 0.0539911273f, 0.2419714457f,
        0.3989434694f,
        0.2419714457f, 0.0539911273f, 0.0044318617f, 0.000133831f };

    const int b     = blockIdx.x >> 4;
    const int chunk = blockIdx.x & 15;
    const int t0    = chunk * 64;
    const int f     = threadIdx.x;
    const float* xbase = x + (size_t)b * T_STEPS * F_IN;

    for (int r = 0; r < 64; r++) {
        int t = t0 + r;
        float acc = 0.0f;
        #pragma unroll
        for (int d = 0; d < 9; d++) {
            int ts = t + d - 4;
            ts = min(max(ts, 0), T_STEPS - 1);
            acc += kk[d] * xbase[ts * F_IN + f];
        }
        tb[r][f] = acc;
    }
    __syncthreads();
    for (int r = 0; r < 64; r++) {
        float acc = 0.0f;
        #pragma unroll
        for (int d = 0; d < 9; d++) {
            int fs = f + d - 4;
            fs = min(max(fs, 0), F_IN - 1);
            acc += kk[d] * tb[r][fs];
        }
        xb[((size_t)b * T_STEPS + t0 + r) * F_IN + f] = f2bf(acc);
    }
}

// ---------------------------------------------------------------------------
// Persistent LSTM. 256 blocks x 256 threads. h exchanged as tagged dwords
// {tag:16, bf16:16}, double-buffered by step parity, via sc0 sc1 (MALL-
// coherent) accesses. hbuf is ZEROED by hipMemsetAsync before launch:
// tag 0 == expected tag at t=0, payload 0 == h0. Publish at step t carries
// tag t+1 (1..1024, never 0, never 0xAAAA). Readers poll for EXACT tag
// equality -> poison (0xAAAA), stale (t-2, 0) and any garbage all fail the
// match. No atomics, no fences, no buffer_inv/wbl2 anywhere in the loop.
// ---------------------------------------------------------------------------
__global__ __launch_bounds__(256, 1) void lstm_persist(
    const unsigned short* __restrict__ xb,   // [64][1024][256] bf16
    const float* __restrict__ Whh,           // [4096][1024]
    const float* __restrict__ Wih,           // [4096][256]
    const float* __restrict__ bih,           // [4096]
    const float* __restrict__ bhh,           // [4096]
    unsigned int* __restrict__ hbuf)         // [2][64][1024] tagged dwords
{
    const int wg   = blockIdx.x;
    const int grp  = wg >> 6;
    const int w    = wg & 63;
    const int tid  = threadIdx.x;
    const int q    = tid >> 6;        // wave id = K-quarter
    const int lane = tid & 63;
    const int lrow = lane & 15;       // A: m-row / B: n-col (batch)
    const int lq   = lane >> 4;       // quad

    __shared__ f32x4 part[2][4][4][64];  // [step parity][q][gate][lane]

    // ---- load weight fragments (one-time), fp32 -> bf16 ----
    bf16x8 wa[8][4];   // [kt][gate]  K-quarter of W_hh
    bf16x8 wx[2][4];   // [kt][gate]  K-quarter of W_ih
    const int row_lo = w * 16 + lrow;
    #pragma unroll
    for (int kt = 0; kt < 8; kt++) {
        const int kofs = q * 256 + kt * 32 + lq * 8;
        #pragma unroll
        for (int g = 0; g < 4; g++) {
            const float* src = Whh + (size_t)(g * H_SZ + row_lo) * H_SZ + kofs;
            union { bf16x8 v; unsigned short s[8]; } u;
            #pragma unroll
            for (int j = 0; j < 8; j++) u.s[j] = f2bf(src[j]);
            wa[kt][g] = u.v;
        }
    }
    #pragma unroll
    for (int kt = 0; kt < 2; kt++) {
        const int kofs = q * 64 + kt * 32 + lq * 8;
        #pragma unroll
        for (int g = 0; g < 4; g++) {
            const float* src = Wih + (size_t)(g * H_SZ + row_lo) * F_IN + kofs;
            union { bf16x8 v; unsigned short s[8]; } u;
            #pragma unroll
            for (int j = 0; j < 8; j++) u.s[j] = f2bf(src[j]);
            wx[kt][g] = u.v;
        }
    }

    // ---- per-thread update-phase state: thread <-> (hid,batch) fixed ----
    const int uhid = tid & 15;
    const int ub   = tid >> 4;
    float bias[4];
    #pragma unroll
    for (int g = 0; g < 4; g++) {
        int r = g * H_SZ + w * 16 + uhid;
        bias[g] = bih[r] + bhh[r];
    }
    float c_reg = 0.0f;

    const int b_abs_l = grp * NB + lrow;   // batch for B-frags (this lane)
    const unsigned short* xrow_base =
        xb + ((size_t)b_abs_l * T_STEPS) * F_IN + q * 64 + lq * 8;
    unsigned int* hdst0 =
        hbuf + (size_t)(grp * NB + ub) * H_SZ + w * 16 + uhid;

    for (int t = 0; t < T_STEPS; t++) {
        // ---- x fragment: normal cached loads ----
        const unsigned short* xrow = xrow_base + (size_t)t * F_IN;
        bf16x8 xf0 = *reinterpret_cast<const bf16x8*>(xrow);
        bf16x8 xf1 = *reinterpret_cast<const bf16x8*>(xrow + 32);

        // ---- poll tagged h_t from MALL until all 64 tags == t ----
        const unsigned int* hprev =
            hbuf + ((size_t)((t + 1) & 1) * 64 + b_abs_l) * H_SZ
                 + q * 256 + lq * 8;
        const unsigned int expect = (unsigned)t;
        i32x4 d0, d1, d2, d3, d4, d5, d6, d7;
        i32x4 d8, d9, d10, d11, d12, d13, d14, d15;
        for (;;) {
            asm volatile(
                "global_load_dwordx4 %0,  %16, off sc0 sc1\n\t"
                "global_load_dwordx4 %1,  %16, off offset:16 sc0 sc1\n\t"
                "global_load_dwordx4 %2,  %16, off offset:128 sc0 sc1\n\t"
                "global_load_dwordx4 %3,  %16, off offset:144 sc0 sc1\n\t"
                "global_load_dwordx4 %4,  %16, off offset:256 sc0 sc1\n\t"
                "global_load_dwordx4 %5,  %16, off offset:272 sc0 sc1\n\t"
                "global_load_dwordx4 %6,  %16, off offset:384 sc0 sc1\n\t"
                "global_load_dwordx4 %7,  %16, off offset:400 sc0 sc1\n\t"
                "global_load_dwordx4 %8,  %16, off offset:512 sc0 sc1\n\t"
                "global_load_dwordx4 %9,  %16, off offset:528 sc0 sc1\n\t"
                "global_load_dwordx4 %10, %16, off offset:640 sc0 sc1\n\t"
                "global_load_dwordx4 %11, %16, off offset:656 sc0 sc1\n\t"
                "global_load_dwordx4 %12, %16, off offset:768 sc0 sc1\n\t"
                "global_load_dwordx4 %13, %16, off offset:784 sc0 sc1\n\t"
                "global_load_dwordx4 %14, %16, off offset:896 sc0 sc1\n\t"
                "global_load_dwordx4 %15, %16, off offset:912 sc0 sc1\n\t"
                "s_waitcnt vmcnt(0)"
                : "=&v"(d0), "=&v"(d1), "=&v"(d2), "=&v"(d3),
                  "=&v"(d4), "=&v"(d5), "=&v"(d6), "=&v"(d7),
                  "=&v"(d8), "=&v"(d9), "=&v"(d10), "=&v"(d11),
                  "=&v"(d12), "=&v"(d13), "=&v"(d14), "=&v"(d15)
                : "v"(hprev)
                : "memory");
            // exact match: OR-accumulate (hi16 XOR expect); zero iff all fresh
            unsigned bad = 0u;
            const i32x4* dv[16] = { &d0,&d1,&d2,&d3,&d4,&d5,&d6,&d7,
                                    &d8,&d9,&d10,&d11,&d12,&d13,&d14,&d15 };
            #pragma unroll
            for (int i = 0; i < 16; i++)
                #pragma unroll
                for (int j = 0; j < 4; j++)
                    bad |= (((unsigned)((*dv[i])[j])) >> 16) ^ expect;
            if (__all((int)(bad == 0u))) break;
            __builtin_amdgcn_s_sleep(1);
        }

        // ---- pack low16 (bf16 h) pairs into MFMA B-fragments ----
        bf16x8 hfa[8];
        {
            const i32x4* dv[16] = { &d0,&d1,&d2,&d3,&d4,&d5,&d6,&d7,
                                    &d8,&d9,&d10,&d11,&d12,&d13,&d14,&d15 };
            #pragma unroll
            for (int kt = 0; kt < 8; kt++) {
                const unsigned* a = (const unsigned*)dv[2 * kt];
                const unsigned* b = (const unsigned*)dv[2 * kt + 1];
                union { bf16x8 v; unsigned u32[4]; } u;
                u.u32[0] = __builtin_amdgcn_perm(a[1], a[0], 0x05040100);
                u.u32[1] = __builtin_amdgcn_perm(a[3], a[2], 0x05040100);
                u.u32[2] = __builtin_amdgcn_perm(b[1], b[0], 0x05040100);
                u.u32[3] = __builtin_amdgcn_perm(b[3], b[2], 0x05040100);
                hfa[kt] = u.v;
            }
        }

        // ---- MFMA: gates partial over this wave's K range ----
        f32x4 acc[4];
        #pragma unroll
        for (int g = 0; g < 4; g++) acc[g] = (f32x4){0.f, 0.f, 0.f, 0.f};
        #pragma unroll
        for (int kt = 0; kt < 8; kt++)
            #pragma unroll
            for (int g = 0; g < 4; g++)
                acc[g] = __builtin_amdgcn_mfma_f32_16x16x32_bf16(
                    wa[kt][g], hfa[kt], acc[g], 0, 0, 0);
        #pragma unroll
        for (int g = 0; g < 4; g++)
            acc[g] = __builtin_amdgcn_mfma_f32_16x16x32_bf16(
                wx[0][g], xf0, acc[g], 0, 0, 0);
        #pragma unroll
        for (int g = 0; g < 4; g++)
            acc[g] = __builtin_amdgcn_mfma_f32_16x16x32_bf16(
                wx[1][g], xf1, acc[g], 0, 0, 0);

        // ---- cross-wave K reduction via LDS (parity-double-buffered) ----
        #pragma unroll
        for (int g = 0; g < 4; g++)
            part[t & 1][q][g][lane] = acc[g];
        __syncthreads();

        // ---- gates + state update (thread = (hid=uhid, batch=ub)) ----
        float gv[4];
        #pragma unroll
        for (int g = 0; g < 4; g++) {
            float s = bias[g];
            #pragma unroll
            for (int qq = 0; qq < 4; qq++)
                s += part[t & 1][qq][g][(uhid >> 2) * 16 + ub][uhid & 3];
            gv[g] = s;
        }
        float ig = fsigmoid(gv[0]);
        float fg = fsigmoid(gv[1]);
        float gg = ftanh(gv[2]);
        float og = fsigmoid(gv[3]);
        c_reg = fg * c_reg + ig * gg;
        float hv = og * ftanh(c_reg);

        // ---- publish tagged h (tag = t+1): fire-and-forget sc0 sc1 store --
        // (drained by next poll's vmcnt(0), or the final drain below)
        unsigned int word = (((unsigned)t + 1u) << 16) | (unsigned)f2bf(hv);
        unsigned int* dst = hdst0 + (size_t)(t & 1) * 64 * H_SZ;
        asm volatile("global_store_dword %0, %1, off sc0 sc1"
                     :: "v"(dst), "v"(word) : "memory");
    }

    // drain the t=1023 publish before s_endpgm (visible to final_fc; never
    // lands after the harness re-poisons the workspace on graph replay)
    asm volatile("s_waitcnt vmcnt(0)" ::: "memory");
}

// ---------------------------------------------------------------------------
// out[b][o] = h_last[b] . W_fc[o] + b_fc[o].  64 blocks x 256 threads.
// h_last = step-1023 publish = parity 1, tag 1024, low 16 = bf16.
// Reads via sc0 sc1 so stale per-XCD L2 lines can never be served.
// ---------------------------------------------------------------------------
__global__ __launch_bounds__(256) void final_fc(
    const unsigned int* __restrict__ hbuf,
    const float* __restrict__ Wfc, const float* __restrict__ bfc,
    float* __restrict__ out)
{
    __shared__ float hs[H_SZ];
    const int b = blockIdx.x;
    const unsigned int* hrow = hbuf + (size_t)64 * H_SZ + (size_t)b * H_SZ;
    {
        const unsigned int* src = hrow + threadIdx.x * 4;
        i32x4 hv4;
        asm volatile("global_load_dwordx4 %0, %1, off sc0 sc1\n\t"
                     "s_waitcnt vmcnt(0)"
                     : "=v"(hv4) : "v"(src) : "memory");
        #pragma unroll
        for (int j = 0; j < 4; j++) {
            union { unsigned u; float f; } cv;
            cv.u = (((unsigned)hv4[j]) & 0xffffu) << 16;
            hs[threadIdx.x * 4 + j] = cv.f;
        }
    }
    __syncthreads();
    const int o = threadIdx.x;
    const float4* wr = reinterpret_cast<const float4*>(Wfc + (size_t)o * H_SZ);
    float acc = bfc[o];
    for (int k4 = 0; k4 < H_SZ / 4; k4++) {
        float4 wv = wr[k4];
        acc += hs[k4 * 4 + 0] * wv.x + hs[k4 * 4 + 1] * wv.y
             + hs[k4 * 4 + 2] * wv.z + hs[k4 * 4 + 3] * wv.w;
    }
    out[(size_t)b * 256 + o] = acc;
}

// ---------------------------------------------------------------------------
extern "C" void kernel_launch(void* const* d_in, const int* in_sizes, int n_in,
                              void* d_out, int out_size, void* d_ws,
                              size_t ws_size, hipStream_t stream)
{
    (void)in_sizes; (void)n_in; (void)out_size; (void)ws_size;
    const float* x   = (const float*)d_in[0];
    const float* Wih = (const float*)d_in[1];
    const float* Whh = (const float*)d_in[2];
    const float* bih = (const float*)d_in[3];
    const float* bhh = (const float*)d_in[4];
    const float* Wfc = (const float*)d_in[5];
    const float* bfc = (const float*)d_in[6];
    float* out = (float*)d_out;

    char* ws = (char*)d_ws;
    unsigned short* xblur = (unsigned short*)ws;                 // 33,554,432 B
    unsigned int*   hbuf  = (unsigned int*)(ws + 33554432);      //    524,288 B

    // zero-init hbuf: tag 0 == expected tag at t=0, payload == h0 = 0.0
    hipMemsetAsync(hbuf, 0, 524288, stream);

    blur_kernel<<<dim3(1024), dim3(256), 0, stream>>>(x, xblur);

    void* kargs[] = { (void*)&xblur, (void*)&Whh, (void*)&Wih,
                      (void*)&bih, (void*)&bhh, (void*)&hbuf };
    hipError_t ce = hipLaunchCooperativeKernel((void*)lstm_persist, dim3(256),
                                               dim3(256), kargs, 0, stream);
    if (ce != hipSuccess) {
        // silent coop-launch rejection (round-3/4 failure mode): fall back to
        // a plain launch. Co-residency is capacity-guaranteed: 32 KB LDS,
        // <=512 VGPR, 256-thread blocks -> >=1 block/CU x 256 CUs = grid.
        (void)hipGetLastError();   // clear error state
        lstm_persist<<<dim3(256), dim3(256), 0, stream>>>(
            xblur, Whh, Wih, bih, bhh, hbuf);
    }

    final_fc<<<dim3(64), dim3(256), 0, stream>>>(hbuf, Wfc, bfc, out);
}

// Round 6
// 5708.978 us; speedup vs baseline: 1.1433x; 1.1433x over previous
//
#include <hip/hip_runtime.h>

typedef __bf16 bf16x8 __attribute__((ext_vector_type(8)));
typedef float f32x4 __attribute__((ext_vector_type(4)));
typedef int i32x4 __attribute__((ext_vector_type(4)));

#define T_STEPS 1024
#define H_SZ    1024
#define F_IN    256
#define NB      16   // batches per group

__device__ __forceinline__ unsigned short f2bf(float f) {
    union { float f; unsigned u; } v; v.f = f;
    unsigned r = v.u + 0x7fffu + ((v.u >> 16) & 1u);
    return (unsigned short)(r >> 16);
}

__device__ __forceinline__ float fsigmoid(float x) {
    return 1.0f / (1.0f + __expf(-x));
}
__device__ __forceinline__ float ftanh(float x) {
    return 1.0f - 2.0f / (__expf(2.0f * x) + 1.0f);
}

// ---------------------------------------------------------------------------
// Gaussian blur (sigma=1, radius=4, edge padding), both axes fused.
// ---------------------------------------------------------------------------
__global__ __launch_bounds__(256) void blur_kernel(
    const float* __restrict__ x, unsigned short* __restrict__ xb)
{
    __shared__ float tb[64][256];
    const float kk[9] = {
        0.000133831f, 0.0044318617f, 0.0539911273f, 0.2419714457f,
        0.3989434694f,
        0.2419714457f, 0.0539911273f, 0.0044318617f, 0.000133831f };

    const int b     = blockIdx.x >> 4;
    const int chunk = blockIdx.x & 15;
    const int t0    = chunk * 64;
    const int f     = threadIdx.x;
    const float* xbase = x + (size_t)b * T_STEPS * F_IN;

    for (int r = 0; r < 64; r++) {
        int t = t0 + r;
        float acc = 0.0f;
        #pragma unroll
        for (int d = 0; d < 9; d++) {
            int ts = t + d - 4;
            ts = min(max(ts, 0), T_STEPS - 1);
            acc += kk[d] * xbase[ts * F_IN + f];
        }
        tb[r][f] = acc;
    }
    __syncthreads();
    for (int r = 0; r < 64; r++) {
        float acc = 0.0f;
        #pragma unroll
        for (int d = 0; d < 9; d++) {
            int fs = f + d - 4;
            fs = min(max(fs, 0), F_IN - 1);
            acc += kk[d] * tb[r][fs];
        }
        xb[((size_t)b * T_STEPS + t0 + r) * F_IN + f] = f2bf(acc);
    }
}

// ---------------------------------------------------------------------------
// Persistent LSTM. 256 blocks x 256 threads. h exchanged as tagged dwords
// {tag:16, bf16:16}, double-buffered by step parity, via sc0 sc1 (MALL-
// coherent) accesses. hbuf+flags ZEROED before launch (tag 0 = h0 = 0).
//
// Sync protocol (no atomics, no fences, no buffer_inv/wbl2):
//  - READINESS HINT: per-WG flag dword (64 B-padded). Publisher stores
//    flag=t+1 after issuing its h stores (unordered wrt them). Readers poll
//    flags >= t (">=" is required: max inter-WG skew is 1 step, and "=="
//    deadlocks when a fast WG bumps its flag past a slow poller).
//  - CORRECTNESS: per-dword tags. After the flag gate, read the h fragment
//    once and validate all tags == t in-register; retry on mismatch (absorbs
//    the unordered flag/data store race). The WAR-safety proof from round 5
//    is unchanged: validation covers all 16384 group dwords, so a WG can
//    overwrite tag-t data (with tag t+2) only after every group WG finished
//    reading tag-t data.
// ---------------------------------------------------------------------------
__global__ __launch_bounds__(256, 1) void lstm_persist(
    const unsigned short* __restrict__ xb,   // [64][1024][256] bf16
    const float* __restrict__ Whh,           // [4096][1024]
    const float* __restrict__ Wih,           // [4096][256]
    const float* __restrict__ bih,           // [4096]
    const float* __restrict__ bhh,           // [4096]
    unsigned int* __restrict__ hbuf,         // [2][64][1024] tagged dwords
    unsigned int* __restrict__ flags)        // [4][64][16] dwords (64B pad)
{
    const int wg   = blockIdx.x;
    const int grp  = wg >> 6;
    const int w    = wg & 63;
    const int tid  = threadIdx.x;
    const int q    = tid >> 6;        // wave id = K-quarter
    const int lane = tid & 63;
    const int lrow = lane & 15;       // A: m-row / B: n-col (batch)
    const int lq   = lane >> 4;       // quad

    __shared__ f32x4 part[2][4][4][64];  // [step parity][q][gate][lane]

    // ---- load weight fragments (one-time), fp32 -> bf16 ----
    bf16x8 wa[8][4];   // [kt][gate]  K-quarter of W_hh
    bf16x8 wx[2][4];   // [kt][gate]  K-quarter of W_ih
    const int row_lo = w * 16 + lrow;
    #pragma unroll
    for (int kt = 0; kt < 8; kt++) {
        const int kofs = q * 256 + kt * 32 + lq * 8;
        #pragma unroll
        for (int g = 0; g < 4; g++) {
            const float* src = Whh + (size_t)(g * H_SZ + row_lo) * H_SZ + kofs;
            union { bf16x8 v; unsigned short s[8]; } u;
            #pragma unroll
            for (int j = 0; j < 8; j++) u.s[j] = f2bf(src[j]);
            wa[kt][g] = u.v;
        }
    }
    #pragma unroll
    for (int kt = 0; kt < 2; kt++) {
        const int kofs = q * 64 + kt * 32 + lq * 8;
        #pragma unroll
        for (int g = 0; g < 4; g++) {
            const float* src = Wih + (size_t)(g * H_SZ + row_lo) * F_IN + kofs;
            union { bf16x8 v; unsigned short s[8]; } u;
            #pragma unroll
            for (int j = 0; j < 8; j++) u.s[j] = f2bf(src[j]);
            wx[kt][g] = u.v;
        }
    }

    // ---- per-thread update-phase state: thread <-> (hid,batch) fixed ----
    const int uhid = tid & 15;
    const int ub   = tid >> 4;
    float bias[4];
    #pragma unroll
    for (int g = 0; g < 4; g++) {
        int r = g * H_SZ + w * 16 + uhid;
        bias[g] = bih[r] + bhh[r];
    }
    float c_reg = 0.0f;

    const int b_abs_l = grp * NB + lrow;   // batch for B-frags (this lane)
    const unsigned short* xrow_base =
        xb + ((size_t)b_abs_l * T_STEPS) * F_IN + q * 64 + lq * 8;
    unsigned int* hdst0 =
        hbuf + (size_t)(grp * NB + ub) * H_SZ + w * 16 + uhid;
    const unsigned int* flag_rd = flags + (((size_t)grp << 6) + lane) * 16;
    unsigned int* flag_wr = flags + (((size_t)grp << 6) + w) * 16;

    for (int t = 0; t < T_STEPS; t++) {
        // ---- x fragment: normal cached loads ----
        const unsigned short* xrow = xrow_base + (size_t)t * F_IN;
        bf16x8 xf0 = *reinterpret_cast<const bf16x8*>(xrow);
        bf16x8 xf1 = *reinterpret_cast<const bf16x8*>(xrow + 32);

        // ---- flag gate: cheap 4 B/lane poll until all 64 WGs >= t ----
        {
            for (;;) {
                unsigned fv;
                asm volatile("global_load_dword %0, %1, off sc0 sc1\n\t"
                             "s_waitcnt vmcnt(0)"
                             : "=v"(fv) : "v"(flag_rd) : "memory");
                if (__all((int)(fv >= (unsigned)t))) break;
                __builtin_amdgcn_s_sleep(1);
            }
        }

        // ---- one-shot tagged h read + in-register validation ----
        const unsigned int* hprev =
            hbuf + ((size_t)((t + 1) & 1) * 64 + b_abs_l) * H_SZ
                 + q * 256 + lq * 8;
        const unsigned int expect = (unsigned)t;
        i32x4 d0, d1, d2, d3, d4, d5, d6, d7;
        i32x4 d8, d9, d10, d11, d12, d13, d14, d15;
        for (;;) {
            asm volatile(
                "global_load_dwordx4 %0,  %16, off sc0 sc1\n\t"
                "global_load_dwordx4 %1,  %16, off offset:16 sc0 sc1\n\t"
                "global_load_dwordx4 %2,  %16, off offset:128 sc0 sc1\n\t"
                "global_load_dwordx4 %3,  %16, off offset:144 sc0 sc1\n\t"
                "global_load_dwordx4 %4,  %16, off offset:256 sc0 sc1\n\t"
                "global_load_dwordx4 %5,  %16, off offset:272 sc0 sc1\n\t"
                "global_load_dwordx4 %6,  %16, off offset:384 sc0 sc1\n\t"
                "global_load_dwordx4 %7,  %16, off offset:400 sc0 sc1\n\t"
                "global_load_dwordx4 %8,  %16, off offset:512 sc0 sc1\n\t"
                "global_load_dwordx4 %9,  %16, off offset:528 sc0 sc1\n\t"
                "global_load_dwordx4 %10, %16, off offset:640 sc0 sc1\n\t"
                "global_load_dwordx4 %11, %16, off offset:656 sc0 sc1\n\t"
                "global_load_dwordx4 %12, %16, off offset:768 sc0 sc1\n\t"
                "global_load_dwordx4 %13, %16, off offset:784 sc0 sc1\n\t"
                "global_load_dwordx4 %14, %16, off offset:896 sc0 sc1\n\t"
                "global_load_dwordx4 %15, %16, off offset:912 sc0 sc1\n\t"
                "s_waitcnt vmcnt(0)"
                : "=&v"(d0), "=&v"(d1), "=&v"(d2), "=&v"(d3),
                  "=&v"(d4), "=&v"(d5), "=&v"(d6), "=&v"(d7),
                  "=&v"(d8), "=&v"(d9), "=&v"(d10), "=&v"(d11),
                  "=&v"(d12), "=&v"(d13), "=&v"(d14), "=&v"(d15)
                : "v"(hprev)
                : "memory");
            unsigned bad = 0u;
            const i32x4* dv[16] = { &d0,&d1,&d2,&d3,&d4,&d5,&d6,&d7,
                                    &d8,&d9,&d10,&d11,&d12,&d13,&d14,&d15 };
            #pragma unroll
            for (int i = 0; i < 16; i++)
                #pragma unroll
                for (int j = 0; j < 4; j++)
                    bad |= (((unsigned)((*dv[i])[j])) >> 16) ^ expect;
            if (__all((int)(bad == 0u))) break;
            __builtin_amdgcn_s_sleep(1);
        }

        // ---- pack low16 (bf16 h) pairs into MFMA B-fragments ----
        bf16x8 hfa[8];
        {
            const i32x4* dv[16] = { &d0,&d1,&d2,&d3,&d4,&d5,&d6,&d7,
                                    &d8,&d9,&d10,&d11,&d12,&d13,&d14,&d15 };
            #pragma unroll
            for (int kt = 0; kt < 8; kt++) {
                const unsigned* a = (const unsigned*)dv[2 * kt];
                const unsigned* b = (const unsigned*)dv[2 * kt + 1];
                union { bf16x8 v; unsigned u32[4]; } u;
                u.u32[0] = __builtin_amdgcn_perm(a[1], a[0], 0x05040100);
                u.u32[1] = __builtin_amdgcn_perm(a[3], a[2], 0x05040100);
                u.u32[2] = __builtin_amdgcn_perm(b[1], b[0], 0x05040100);
                u.u32[3] = __builtin_amdgcn_perm(b[3], b[2], 0x05040100);
                hfa[kt] = u.v;
            }
        }

        // ---- MFMA: gates partial over this wave's K range ----
        f32x4 acc[4];
        #pragma unroll
        for (int g = 0; g < 4; g++) acc[g] = (f32x4){0.f, 0.f, 0.f, 0.f};
        #pragma unroll
        for (int kt = 0; kt < 8; kt++)
            #pragma unroll
            for (int g = 0; g < 4; g++)
                acc[g] = __builtin_amdgcn_mfma_f32_16x16x32_bf16(
                    wa[kt][g], hfa[kt], acc[g], 0, 0, 0);
        #pragma unroll
        for (int g = 0; g < 4; g++)
            acc[g] = __builtin_amdgcn_mfma_f32_16x16x32_bf16(
                wx[0][g], xf0, acc[g], 0, 0, 0);
        #pragma unroll
        for (int g = 0; g < 4; g++)
            acc[g] = __builtin_amdgcn_mfma_f32_16x16x32_bf16(
                wx[1][g], xf1, acc[g], 0, 0, 0);

        // ---- cross-wave K reduction via LDS (parity-double-buffered) ----
        #pragma unroll
        for (int g = 0; g < 4; g++)
            part[t & 1][q][g][lane] = acc[g];
        __syncthreads();

        // ---- gates + state update (thread = (hid=uhid, batch=ub)) ----
        float gv[4];
        #pragma unroll
        for (int g = 0; g < 4; g++) {
            float s = bias[g];
            #pragma unroll
            for (int qq = 0; qq < 4; qq++)
                s += part[t & 1][qq][g][(uhid >> 2) * 16 + ub][uhid & 3];
            gv[g] = s;
        }
        float ig = fsigmoid(gv[0]);
        float fg = fsigmoid(gv[1]);
        float gg = ftanh(gv[2]);
        float og = fsigmoid(gv[3]);
        c_reg = fg * c_reg + ig * gg;
        float hv = og * ftanh(c_reg);

        // ---- publish tagged h (tag = t+1) + flag, fire-and-forget ----
        unsigned int word = (((unsigned)t + 1u) << 16) | (unsigned)f2bf(hv);
        unsigned int* dst = hdst0 + (size_t)(t & 1) * 64 * H_SZ;
        asm volatile("global_store_dword %0, %1, off sc0 sc1"
                     :: "v"(dst), "v"(word) : "memory");
        if (tid == 0) {
            unsigned fw = (unsigned)t + 1u;
            asm volatile("global_store_dword %0, %1, off sc0 sc1"
                         :: "v"(flag_wr), "v"(fw) : "memory");
        }
    }

    // drain the t=1023 publishes before s_endpgm (visible to final_fc; never
    // lands after the harness re-poisons the workspace on graph replay)
    asm volatile("s_waitcnt vmcnt(0)" ::: "memory");
}

// ---------------------------------------------------------------------------
// out[b][o] = h_last[b] . W_fc[o] + b_fc[o].  64 blocks x 256 threads.
// h_last = step-1023 publish = parity 1, tag 1024, low 16 = bf16.
// Reads via sc0 sc1 so stale per-XCD L2 lines can never be served.
// ---------------------------------------------------------------------------
__global__ __launch_bounds__(256) void final_fc(
    const unsigned int* __restrict__ hbuf,
    const float* __restrict__ Wfc, const float* __restrict__ bfc,
    float* __restrict__ out)
{
    __shared__ float hs[H_SZ];
    const int b = blockIdx.x;
    const unsigned int* hrow = hbuf + (size_t)64 * H_SZ + (size_t)b * H_SZ;
    {
        const unsigned int* src = hrow + threadIdx.x * 4;
        i32x4 hv4;
        asm volatile("global_load_dwordx4 %0, %1, off sc0 sc1\n\t"
                     "s_waitcnt vmcnt(0)"
                     : "=v"(hv4) : "v"(src) : "memory");
        #pragma unroll
        for (int j = 0; j < 4; j++) {
            union { unsigned u; float f; } cv;
            cv.u = (((unsigned)hv4[j]) & 0xffffu) << 16;
            hs[threadIdx.x * 4 + j] = cv.f;
        }
    }
    __syncthreads();
    const int o = threadIdx.x;
    const float4* wr = reinterpret_cast<const float4*>(Wfc + (size_t)o * H_SZ);
    float acc = bfc[o];
    for (int k4 = 0; k4 < H_SZ / 4; k4++) {
        float4 wv = wr[k4];
        acc += hs[k4 * 4 + 0] * wv.x + hs[k4 * 4 + 1] * wv.y
             + hs[k4 * 4 + 2] * wv.z + hs[k4 * 4 + 3] * wv.w;
    }
    out[(size_t)b * 256 + o] = acc;
}

// ---------------------------------------------------------------------------
extern "C" void kernel_launch(void* const* d_in, const int* in_sizes, int n_in,
                              void* d_out, int out_size, void* d_ws,
                              size_t ws_size, hipStream_t stream)
{
    (void)in_sizes; (void)n_in; (void)out_size; (void)ws_size;
    const float* x   = (const float*)d_in[0];
    const float* Wih = (const float*)d_in[1];
    const float* Whh = (const float*)d_in[2];
    const float* bih = (const float*)d_in[3];
    const float* bhh = (const float*)d_in[4];
    const float* Wfc = (const float*)d_in[5];
    const float* bfc = (const float*)d_in[6];
    float* out = (float*)d_out;

    char* ws = (char*)d_ws;
    unsigned short* xblur = (unsigned short*)ws;                 // 33,554,432 B
    unsigned int*   hbuf  = (unsigned int*)(ws + 33554432);      //    524,288 B
    unsigned int*   flags = (unsigned int*)(ws + 33554432 + 524288); // 16,384 B

    // zero-init hbuf+flags: tag 0 == expected at t=0, payload == h0 = 0.0
    hipMemsetAsync(hbuf, 0, 524288 + 16384, stream);

    blur_kernel<<<dim3(1024), dim3(256), 0, stream>>>(x, xblur);

    void* kargs[] = { (void*)&xblur, (void*)&Whh, (void*)&Wih,
                      (void*)&bih, (void*)&bhh, (void*)&hbuf, (void*)&flags };
    hipError_t ce = hipLaunchCooperativeKernel((void*)lstm_persist, dim3(256),
                                               dim3(256), kargs, 0, stream);
    if (ce != hipSuccess) {
        (void)hipGetLastError();   // clear error state
        // co-residency capacity-guaranteed: 32 KB LDS, <=512 VGPR,
        // 256-thread blocks -> >=1 block/CU x 256 CUs = grid
        lstm_persist<<<dim3(256), dim3(256), 0, stream>>>(
            xblur, Whh, Wih, bih, bhh, hbuf, flags);
    }

    final_fc<<<dim3(64), dim3(256), 0, stream>>>(hbuf, Wfc, bfc, out);
}

// Round 7
// 5039.309 us; speedup vs baseline: 1.2952x; 1.1329x over previous
//
#include <hip/hip_runtime.h>

typedef __bf16 bf16x8 __attribute__((ext_vector_type(8)));
typedef float f32x4 __attribute__((ext_vector_type(4)));
typedef int i32x2 __attribute__((ext_vector_type(2)));

#define T_STEPS 1024
#define H_SZ    1024
#define F_IN    256
#define NB      16   // batches per group

__device__ __forceinline__ unsigned short f2bf(float f) {
    union { float f; unsigned u; } v; v.f = f;
    unsigned r = v.u + 0x7fffu + ((v.u >> 16) & 1u);
    return (unsigned short)(r >> 16);
}

__device__ __forceinline__ float fsigmoid(float x) {
    return 1.0f / (1.0f + __expf(-x));
}
__device__ __forceinline__ float ftanh(float x) {
    return 1.0f - 2.0f / (__expf(2.0f * x) + 1.0f);
}

// ---------------------------------------------------------------------------
// Gaussian blur (sigma=1, radius=4, edge padding), both axes fused.
// ---------------------------------------------------------------------------
__global__ __launch_bounds__(256) void blur_kernel(
    const float* __restrict__ x, unsigned short* __restrict__ xb)
{
    __shared__ float tb[64][256];
    const float kk[9] = {
        0.000133831f, 0.0044318617f, 0.0539911273f, 0.2419714457f,
        0.3989434694f,
        0.2419714457f, 0.0539911273f, 0.0044318617f, 0.000133831f };

    const int b     = blockIdx.x >> 4;
    const int chunk = blockIdx.x & 15;
    const int t0    = chunk * 64;
    const int f     = threadIdx.x;
    const float* xbase = x + (size_t)b * T_STEPS * F_IN;

    for (int r = 0; r < 64; r++) {
        int t = t0 + r;
        float acc = 0.0f;
        #pragma unroll
        for (int d = 0; d < 9; d++) {
            int ts = t + d - 4;
            ts = min(max(ts, 0), T_STEPS - 1);
            acc += kk[d] * xbase[ts * F_IN + f];
        }
        tb[r][f] = acc;
    }
    __syncthreads();
    for (int r = 0; r < 64; r++) {
        float acc = 0.0f;
        #pragma unroll
        for (int d = 0; d < 9; d++) {
            int fs = f + d - 4;
            fs = min(max(fs, 0), F_IN - 1);
            acc += kk[d] * tb[r][fs];
        }
        xb[((size_t)b * T_STEPS + t0 + r) * F_IN + f] = f2bf(acc);
    }
}

// ---------------------------------------------------------------------------
// Persistent LSTM. 256 blocks x 256 threads. h exchanged as PURE bf16,
// double-buffered by step parity, via sc0 sc1 (MALL-coherent) accesses.
//
// Sync protocol (no atomics, no fences):
//  PUBLISH: every thread stores its bf16 h (sc0 sc1), drains vmcnt(0),
//           __syncthreads, then tid0 stores flag = t+1 (sc0 sc1).
//           => flag t+1 visible IMPLIES the whole WG's h_t+1 is at the MALL.
//  CONSUME: poll the group's 64 flags (one 256 B region, 1 dword/lane)
//           until all >= t (">=" required: provable max skew is 1 step),
//           then ONE direct read of the h fragments. No tags, no retries.
//  WAR:     a WG reaches its step-t+2 publish (overwriting parity buffer
//           read at step t+1) only after poll(t+2): all flags >= t+2, i.e.
//           every group WG finished step t+1 INCLUDING its completed
//           (vmcnt-drained) reads of that buffer. One-step double-buffer
//           slack is exactly sufficient.
// ---------------------------------------------------------------------------
__global__ __launch_bounds__(256, 1) void lstm_persist(
    const unsigned short* __restrict__ xb,   // [64][1024][256] bf16
    const float* __restrict__ Whh,           // [4096][1024]
    const float* __restrict__ Wih,           // [4096][256]
    const float* __restrict__ bih,           // [4096]
    const float* __restrict__ bhh,           // [4096]
    unsigned short* __restrict__ hbuf,       // [2][64][1024] bf16
    unsigned int* __restrict__ flags)        // [4][1024] dwords (4KB/group)
{
    const int wg   = blockIdx.x;
    const int grp  = wg >> 6;
    const int w    = wg & 63;
    const int tid  = threadIdx.x;
    const int q    = tid >> 6;        // wave id = K-quarter
    const int lane = tid & 63;
    const int lrow = lane & 15;       // A: m-row / B: n-col (batch)
    const int lq   = lane >> 4;       // quad

    __shared__ f32x4 part[4][4][64];  // [q][gate][lane] accum fragments

    // ---- load weight fragments (one-time), fp32 -> bf16 ----
    bf16x8 wa[8][4];   // [kt][gate]  K-quarter of W_hh
    bf16x8 wx[2][4];   // [kt][gate]  K-quarter of W_ih
    const int row_lo = w * 16 + lrow;
    #pragma unroll
    for (int kt = 0; kt < 8; kt++) {
        const int kofs = q * 256 + kt * 32 + lq * 8;
        #pragma unroll
        for (int g = 0; g < 4; g++) {
            const float* src = Whh + (size_t)(g * H_SZ + row_lo) * H_SZ + kofs;
            union { bf16x8 v; unsigned short s[8]; } u;
            #pragma unroll
            for (int j = 0; j < 8; j++) u.s[j] = f2bf(src[j]);
            wa[kt][g] = u.v;
        }
    }
    #pragma unroll
    for (int kt = 0; kt < 2; kt++) {
        const int kofs = q * 64 + kt * 32 + lq * 8;
        #pragma unroll
        for (int g = 0; g < 4; g++) {
            const float* src = Wih + (size_t)(g * H_SZ + row_lo) * F_IN + kofs;
            union { bf16x8 v; unsigned short s[8]; } u;
            #pragma unroll
            for (int j = 0; j < 8; j++) u.s[j] = f2bf(src[j]);
            wx[kt][g] = u.v;
        }
    }

    // ---- per-thread update-phase state: thread <-> (hid,batch) fixed ----
    const int uhid = tid & 15;
    const int ub   = tid >> 4;
    float bias[4];
    #pragma unroll
    for (int g = 0; g < 4; g++) {
        int r = g * H_SZ + w * 16 + uhid;
        bias[g] = bih[r] + bhh[r];
    }
    float c_reg = 0.0f;

    const int b_abs_l = grp * NB + lrow;   // batch for B-frags (this lane)
    const unsigned short* xrow_base =
        xb + ((size_t)b_abs_l * T_STEPS) * F_IN + q * 64 + lq * 8;
    unsigned short* hdst0 =
        hbuf + (size_t)(grp * NB + ub) * H_SZ + w * 16 + uhid;
    const unsigned int* flag_rd = flags + ((size_t)grp << 10) + lane;
    unsigned int* flag_wr = flags + ((size_t)grp << 10) + w;

    for (int t = 0; t < T_STEPS; t++) {
        // ---- x fragment: normal cached loads (read-only, L1/L2-warm) ----
        const unsigned short* xrow = xrow_base + (size_t)t * F_IN;
        bf16x8 xf0 = *reinterpret_cast<const bf16x8*>(xrow);
        bf16x8 xf1 = *reinterpret_cast<const bf16x8*>(xrow + 32);

        // ---- flag gate: 1 dword/lane (256 B/group), until all 64 >= t ----
        for (;;) {
            unsigned fv;
            asm volatile("global_load_dword %0, %1, off sc0 sc1\n\t"
                         "s_waitcnt vmcnt(0)"
                         : "=v"(fv) : "v"(flag_rd) : "memory");
            if (__all((int)(fv >= (unsigned)t))) break;
            __builtin_amdgcn_s_sleep(1);
        }

        // ---- ONE direct read of h_t fragments (flag guarantees fresh) ----
        const unsigned short* hprev =
            hbuf + ((size_t)((t + 1) & 1) * 64 + b_abs_l) * H_SZ
                 + q * 256 + lq * 8;
        bf16x8 hf0, hf1, hf2, hf3, hf4, hf5, hf6, hf7;
        asm volatile(
            "global_load_dwordx4 %0, %8, off sc0 sc1\n\t"
            "global_load_dwordx4 %1, %8, off offset:64 sc0 sc1\n\t"
            "global_load_dwordx4 %2, %8, off offset:128 sc0 sc1\n\t"
            "global_load_dwordx4 %3, %8, off offset:192 sc0 sc1\n\t"
            "global_load_dwordx4 %4, %8, off offset:256 sc0 sc1\n\t"
            "global_load_dwordx4 %5, %8, off offset:320 sc0 sc1\n\t"
            "global_load_dwordx4 %6, %8, off offset:384 sc0 sc1\n\t"
            "global_load_dwordx4 %7, %8, off offset:448 sc0 sc1\n\t"
            "s_waitcnt vmcnt(0)"
            : "=&v"(hf0), "=&v"(hf1), "=&v"(hf2), "=&v"(hf3),
              "=&v"(hf4), "=&v"(hf5), "=&v"(hf6), "=&v"(hf7)
            : "v"(hprev)
            : "memory");
        bf16x8 hfa[8] = { hf0, hf1, hf2, hf3, hf4, hf5, hf6, hf7 };

        // ---- MFMA: gates partial over this wave's K range ----
        f32x4 acc[4];
        #pragma unroll
        for (int g = 0; g < 4; g++) acc[g] = (f32x4){0.f, 0.f, 0.f, 0.f};
        #pragma unroll
        for (int kt = 0; kt < 8; kt++)
            #pragma unroll
            for (int g = 0; g < 4; g++)
                acc[g] = __builtin_amdgcn_mfma_f32_16x16x32_bf16(
                    wa[kt][g], hfa[kt], acc[g], 0, 0, 0);
        #pragma unroll
        for (int g = 0; g < 4; g++)
            acc[g] = __builtin_amdgcn_mfma_f32_16x16x32_bf16(
                wx[0][g], xf0, acc[g], 0, 0, 0);
        #pragma unroll
        for (int g = 0; g < 4; g++)
            acc[g] = __builtin_amdgcn_mfma_f32_16x16x32_bf16(
                wx[1][g], xf1, acc[g], 0, 0, 0);

        // ---- cross-wave K reduction via LDS ----
        #pragma unroll
        for (int g = 0; g < 4; g++)
            part[q][g][lane] = acc[g];
        __syncthreads();

        // ---- gates + state update (thread = (hid=uhid, batch=ub)) ----
        float gv[4];
        #pragma unroll
        for (int g = 0; g < 4; g++) {
            float s = bias[g];
            #pragma unroll
            for (int qq = 0; qq < 4; qq++)
                s += part[qq][g][(uhid >> 2) * 16 + ub][uhid & 3];
            gv[g] = s;
        }
        float ig = fsigmoid(gv[0]);
        float fg = fsigmoid(gv[1]);
        float gg = ftanh(gv[2]);
        float og = fsigmoid(gv[3]);
        c_reg = fg * c_reg + ig * gg;
        float hv = og * ftanh(c_reg);

        // ---- publish: store h, DRAIN, barrier, then flag (the guarantee) --
        unsigned short hb = f2bf(hv);
        unsigned short* dst = hdst0 + (size_t)(t & 1) * 64 * H_SZ;
        asm volatile("global_store_short %0, %1, off sc0 sc1\n\t"
                     "s_waitcnt vmcnt(0)"
                     :: "v"(dst), "v"(hb) : "memory");
        __syncthreads();   // all 256 threads' h stores are at the MALL
        if (tid == 0) {
            unsigned fw = (unsigned)t + 1u;
            asm volatile("global_store_dword %0, %1, off sc0 sc1"
                         :: "v"(flag_wr), "v"(fw) : "memory");
        }
    }

    // drain the final flag store before s_endpgm (h stores already drained
    // pre-barrier; nothing may land after the harness re-poisons d_ws)
    asm volatile("s_waitcnt vmcnt(0)" ::: "memory");
}

// ---------------------------------------------------------------------------
// out[b][o] = h_last[b] . W_fc[o] + b_fc[o].  64 blocks x 256 threads.
// h_last = step-1023 publish = parity 1, pure bf16.
// Reads via sc0 sc1 so stale per-XCD L2 lines can never be served.
// ---------------------------------------------------------------------------
__global__ __launch_bounds__(256) void final_fc(
    const unsigned short* __restrict__ hbuf,
    const float* __restrict__ Wfc, const float* __restrict__ bfc,
    float* __restrict__ out)
{
    __shared__ float hs[H_SZ];
    const int b = blockIdx.x;
    const unsigned short* hrow = hbuf + (size_t)64 * H_SZ + (size_t)b * H_SZ;
    {
        const unsigned short* src = hrow + threadIdx.x * 4;
        i32x2 hv2;
        asm volatile("global_load_dwordx2 %0, %1, off sc0 sc1\n\t"
                     "s_waitcnt vmcnt(0)"
                     : "=v"(hv2) : "v"(src) : "memory");
        #pragma unroll
        for (int j = 0; j < 2; j++) {
            unsigned d = (unsigned)hv2[j];
            union { unsigned u; float f; } lo, hi;
            lo.u = (d & 0xffffu) << 16;
            hi.u = d & 0xffff0000u;
            hs[threadIdx.x * 4 + j * 2 + 0] = lo.f;
            hs[threadIdx.x * 4 + j * 2 + 1] = hi.f;
        }
    }
    __syncthreads();
    const int o = threadIdx.x;
    const float4* wr = reinterpret_cast<const float4*>(Wfc + (size_t)o * H_SZ);
    float acc = bfc[o];
    for (int k4 = 0; k4 < H_SZ / 4; k4++) {
        float4 wv = wr[k4];
        acc += hs[k4 * 4 + 0] * wv.x + hs[k4 * 4 + 1] * wv.y
             + hs[k4 * 4 + 2] * wv.z + hs[k4 * 4 + 3] * wv.w;
    }
    out[(size_t)b * 256 + o] = acc;
}

// ---------------------------------------------------------------------------
extern "C" void kernel_launch(void* const* d_in, const int* in_sizes, int n_in,
                              void* d_out, int out_size, void* d_ws,
                              size_t ws_size, hipStream_t stream)
{
    (void)in_sizes; (void)n_in; (void)out_size; (void)ws_size;
    const float* x   = (const float*)d_in[0];
    const float* Wih = (const float*)d_in[1];
    const float* Whh = (const float*)d_in[2];
    const float* bih = (const float*)d_in[3];
    const float* bhh = (const float*)d_in[4];
    const float* Wfc = (const float*)d_in[5];
    const float* bfc = (const float*)d_in[6];
    float* out = (float*)d_out;

    char* ws = (char*)d_ws;
    unsigned short* xblur = (unsigned short*)ws;                 // 33,554,432 B
    unsigned short* hbuf  = (unsigned short*)(ws + 33554432);    //    262,144 B
    unsigned int*   flags = (unsigned int*)(ws + 33554432 + 262144); // 16,384 B

    // zero-init hbuf (h0 = 0.0) + flags (0 == expected at t=0)
    hipMemsetAsync(hbuf, 0, 262144 + 16384, stream);

    blur_kernel<<<dim3(1024), dim3(256), 0, stream>>>(x, xblur);

    void* kargs[] = { (void*)&xblur, (void*)&Whh, (void*)&Wih,
                      (void*)&bih, (void*)&bhh, (void*)&hbuf, (void*)&flags };
    hipError_t ce = hipLaunchCooperativeKernel((void*)lstm_persist, dim3(256),
                                               dim3(256), kargs, 0, stream);
    if (ce != hipSuccess) {
        (void)hipGetLastError();   // clear error state
        // co-residency capacity-guaranteed: 16 KB LDS, ~130 VGPR,
        // 256-thread blocks -> >=1 block/CU x 256 CUs = grid
        lstm_persist<<<dim3(256), dim3(256), 0, stream>>>(
            xblur, Whh, Wih, bih, bhh, hbuf, flags);
    }

    final_fc<<<dim3(64), dim3(256), 0, stream>>>(hbuf, Wfc, bfc, out);
}